// Round 1
// baseline (146.906 us; speedup 1.0000x reference)
//
#include <hip/hip_runtime.h>
#include <math.h>

// CIRNet fully-fused: T=1048576 rows x 18 feats -> r_predicts[N], regs[N], dts[N], N=T-1.
// Single kernel, 256 blocks x 1024 threads (1 block/CU via 157.8KB LDS -> co-resident).
// Per block: 4096 rows staged in 4x1024-row chunks, double-buffered LDS via
// global_load_lds dwordx4 (coalesced; kills prep's 8x VMEM transaction amplification and
// the 17MB dc/seeds HBM round-trip). Coefficients computed 1-row-per-thread (coalesced),
// redistributed to 4-step scan owners through an 8KB LDS buffer. Then the previously
// validated tail: per-thread Newton-linearized affine map -> block scan -> device-scope
// spin barrier -> global scan -> replay + store. FP math order identical to prior kernel.
#define NSTEPS  1048575
#define FEAT    18
#define NB      256                 // blocks (== CUs -> co-resident)
#define NT      1024                // threads per block
#define RPB     (NT * 4)            // 4096 rows per block
#define CROWS   NT                  // 1024 rows per chunk (1 row / thread in compute)
#define NCHUNK  (RPB / CROWS)       // 4
#define CF4     ((CROWS * FEAT) / 4) // 4608 float4 per chunk

#define GLDS16(g, l) \
    __builtin_amdgcn_global_load_lds((const __attribute__((address_space(1))) void*)(g), \
                                     (__attribute__((address_space(3))) void*)(l), 16, 0, 0)

__device__ __forceinline__ void stage_chunk(const float* __restrict__ trace,
                                            long gbase, float* dst, int tid)
{
    const float4* src = (const float4*)(trace + gbase * FEAT);
#pragma unroll
    for (int r = 0; r < 4; ++r) {           // 4*1024 float4
        int i = r * NT + tid;
        GLDS16(src + i, dst + i * 4);
    }
    if (tid < (CF4 - 4 * NT)) {             // remaining 512 float4 (waves 0..7, uniform)
        int i = 4 * NT + tid;
        GLDS16(src + i, dst + i * 4);
    }
}

// one step + derivative-product update (identical math to validated kernel)
#define GSTEP(dd, cc) { \
    float a   = fmaf(-k, (dd), 1.f); \
    float b   = kth * (dd); \
    float ar  = fabsf(r); \
    float sq  = sqrtf(ar); \
    float inv = (ar > 1e-30f) ? rsqrtf(ar) : 0.f; \
    float g   = fmaf(0.5f * (cc), copysignf(inv, r), a); \
    r = fmaf((cc), sq, fmaf(a, r, b)); \
    P *= g; }

#define FSTEP(dd, cc) { \
    float a = fmaf(-k, (dd), 1.f); \
    float b = kth * (dd); \
    rr = fmaf((cc), sqrtf(fabsf(rr)), fmaf(a, rr, b)); }

__device__ __forceinline__ void wave_scan_affine(float& A, float& B, int lane) {
#pragma unroll
    for (int d = 1; d < 64; d <<= 1) {
        float pA = __shfl_up(A, d, 64);
        float pB = __shfl_up(B, d, 64);
        if (lane >= d) { B = fmaf(A, pB, B); A *= pA; }
    }
}

__global__ void __launch_bounds__(NT) cir_fused(
    const float* __restrict__ trace,
    const float* __restrict__ sW, const float* __restrict__ sb,
    const float* __restrict__ eW, const float* __restrict__ kp,
    const float* __restrict__ thp,
    float* __restrict__ out,
    float* __restrict__ gA, float* __restrict__ gB,
    unsigned int* __restrict__ cnt)
{
    __shared__ __align__(16) float  buf[2][CROWS * FEAT];   // 2 x 72KB
    __shared__ __align__(16) float2 dcl[CROWS];             // 8KB (d,c) handoff
    __shared__ float wAs[16], wBs[16];
    __shared__ float sgA[NB], sgB[NB];

    const int tid = threadIdx.x, lane = tid & 63, wid = tid >> 6, bid = blockIdx.x;
    const long blkrow = (long)bid * RPB;

    stage_chunk(trace, blkrow, buf[0], tid);   // chunk 0 in flight

    const float k = kp[0], th = thp[0], kth = k * th;
    const float tkth2 = 2.f * kth;
    const float sb0 = sb[0];
    float sw[8], ew[8];
#pragma unroll
    for (int i = 0; i < 8; ++i) { sw[i] = sW[i]; ew[i] = eW[i]; }
    const float t0 = trace[0], r0v = trace[1];

    float4 q0 = make_float4(0.f, 0.f, 0.f, 0.f);
    float4 q1 = make_float4(0.f, 0.f, 0.f, 0.f);
    float tfirst = 0.f;

    __syncthreads();                           // chunk 0 landed (syncthreads drains vmcnt)

    for (int ch = 0; ch < NCHUNK; ++ch) {
        const float* B = buf[ch & 1];
        if (ch + 1 < NCHUNK)                   // prefetch next chunk into other buffer
            stage_chunk(trace, blkrow + (long)(ch + 1) * CROWS, buf[(ch + 1) & 1], tid);

        // --- coefficients: 1 row per thread, coalesced LDS reads (stride 18 = 4-way) ---
        long n = blkrow + (long)ch * CROWS + tid;
        float dv = 0.f, cv = 0.f;
        if (n < NSTEPS) {
            const float* row = B + tid * FEAT;
            float t  = row[0];
            float tn = (tid < NT - 1) ? row[FEAT] : trace[(n + 1) * FEAT];
            dv = tn - t;
            const float2* f = (const float2*)(row + 2);   // 8B aligned (72*tid+8)
            float2 a0 = f[0], a1 = f[1], a2 = f[2], a3 = f[3];
            float2 b0 = f[4], b1 = f[5], b2 = f[6], b3 = f[7];
            float sig = sb0;
            sig = fmaf(a0.x, sw[0], sig); sig = fmaf(a0.y, sw[1], sig);
            sig = fmaf(a1.x, sw[2], sig); sig = fmaf(a1.y, sw[3], sig);
            sig = fmaf(a2.x, sw[4], sig); sig = fmaf(a2.y, sw[5], sig);
            sig = fmaf(a3.x, sw[6], sig); sig = fmaf(a3.y, sw[7], sig);
            float ep = 0.f;
            ep = fmaf(b0.x, ew[0], ep); ep = fmaf(b0.y, ew[1], ep);
            ep = fmaf(b1.x, ew[2], ep); ep = fmaf(b1.y, ew[3], ep);
            ep = fmaf(b2.x, ew[4], ep); ep = fmaf(b2.y, ew[5], ep);
            ep = fmaf(b3.x, ew[6], ep); ep = fmaf(b3.y, ew[7], ep);
            cv = sig * ep * sqrtf(fabsf(dv));
            out[NSTEPS + n]      = fmaf(-sig, sig, tkth2);   // regs (coalesced)
            out[2L * NSTEPS + n] = dv;                       // dts  (coalesced)
        }                                       // pad step stays (0,0) -> exact identity
        dcl[tid] = make_float2(dv, cv);
        __syncthreads();                        // dcl ready; chunk ch+1 drained

        // --- redistribute to scan owners: thread tid owns global rows 4*(bid*NT+tid).. ---
        if ((tid >> 8) == ch) {
            int tr = tid & 255;
            const float4* dq = (const float4*)dcl;
            q0 = dq[2 * tr];                    // (d0,c0,d1,c1)
            q1 = dq[2 * tr + 1];                // (d2,c2,d3,c3)
            tfirst = B[(4 * tr) * FEAT];        // t of owner's first row
        }
        __syncthreads();                        // dcl consumed before next overwrite
    }

    // ---- tail: identical to validated fused_pass ----
    const int c = bid * NT + tid;
    float s = th + (r0v - th) * __expf(-k * (tfirst - t0));   // closed-form ODE seed
    float r = s, P = 1.f;
    GSTEP(q0.x, q0.y)
    GSTEP(q0.z, q0.w)
    GSTEP(q1.x, q1.y)
    GSTEP(q1.z, q1.w)
    float A = P, Bv = fmaf(-P, s, r);

    float iA = A, iB = Bv;
    wave_scan_affine(iA, iB, lane);
    if (lane == 63) { wAs[wid] = iA; wBs[wid] = iB; }
    __syncthreads();
    if (wid == 0) {
        float aA = (lane < 16) ? wAs[lane] : 1.f;
        float aB = (lane < 16) ? wBs[lane] : 0.f;
        wave_scan_affine(aA, aB, lane);
        if (lane < 16) { wAs[lane] = aA; wBs[lane] = aB; }
    }
    __syncthreads();
    float weA = 1.f, weB = 0.f;
    if (wid > 0) { weA = wAs[wid - 1]; weB = wBs[wid - 1]; }
    float eA = __shfl_up(iA, 1, 64), eB = __shfl_up(iB, 1, 64);
    if (lane == 0) { eA = 1.f; eB = 0.f; }
    float Ate = eA * weA;
    float Bte = fmaf(eA, weB, eB);

    if (tid == 0) {
        __hip_atomic_store(&gA[bid], wAs[15], __ATOMIC_RELAXED, __HIP_MEMORY_SCOPE_AGENT);
        __hip_atomic_store(&gB[bid], wBs[15], __ATOMIC_RELAXED, __HIP_MEMORY_SCOPE_AGENT);
        __hip_atomic_fetch_add(cnt, 1u, __ATOMIC_ACQ_REL, __HIP_MEMORY_SCOPE_AGENT);
        while (__hip_atomic_load(cnt, __ATOMIC_ACQUIRE, __HIP_MEMORY_SCOPE_AGENT) < NB)
            __builtin_amdgcn_s_sleep(1);
    }
    __syncthreads();

    if (tid < NB) {
        sgA[tid] = __hip_atomic_load(&gA[tid], __ATOMIC_RELAXED, __HIP_MEMORY_SCOPE_AGENT);
        sgB[tid] = __hip_atomic_load(&gB[tid], __ATOMIC_RELAXED, __HIP_MEMORY_SCOPE_AGENT);
    }
    __syncthreads();
    for (int d = 1; d < NB; d <<= 1) {
        float pA = 1.f, pB = 0.f;
        bool act = (tid < NB) && (tid >= d);
        if (act) { pA = sgA[tid - d]; pB = sgB[tid - d]; }
        __syncthreads();
        if (act) { sgB[tid] = fmaf(sgA[tid], pB, sgB[tid]); sgA[tid] *= pA; }
        __syncthreads();
    }
    float beA = 1.f, beB = 0.f;
    if (bid > 0) { beA = sgA[bid - 1]; beB = sgB[bid - 1]; }

    float FA = Ate * beA;
    float FB = fmaf(Ate, beB, Bte);
    float rr = fmaf(FA, r0v, FB);
    float4 ov;
    FSTEP(q0.x, q0.y) ov.x = rr;
    FSTEP(q0.z, q0.w) ov.y = rr;
    FSTEP(q1.x, q1.y) ov.z = rr;
    FSTEP(q1.z, q1.w) ov.w = rr;
    int nb = 4 * c;
    if (nb + 4 <= NSTEPS) {
        *(float4*)(out + nb) = ov;
    } else {                        // last thread only (step NSTEPS is pad)
        out[nb + 0] = ov.x;
        out[nb + 1] = ov.y;
        out[nb + 2] = ov.z;
    }
}

extern "C" void kernel_launch(void* const* d_in, const int* in_sizes, int n_in,
                              void* d_out, int out_size, void* d_ws, size_t ws_size,
                              hipStream_t stream)
{
    const float* trace = (const float*)d_in[0];
    const float* sW    = (const float*)d_in[1];
    const float* sb    = (const float*)d_in[2];
    const float* eW    = (const float*)d_in[3];
    const float* kp    = (const float*)d_in[4];
    const float* thp   = (const float*)d_in[5];
    float* out = (float*)d_out;

    float*        gA  = (float*)d_ws;
    float*        gB  = gA + NB;
    unsigned int* cnt = (unsigned int*)(gB + NB);

    hipMemsetAsync(cnt, 0, sizeof(unsigned int), stream);   // graph-capture-legal memset node
    cir_fused<<<NB, NT, 0, stream>>>(trace, sW, sb, eW, kp, thp, out, gA, gB, cnt);
}